// Round 1
// baseline (85.934 us; speedup 1.0000x reference)
//
#include <hip/hip_runtime.h>
#include <hip/hip_bf16.h>
#include <math.h>

// Problem constants (B,U,D) = (4096, 256, 128)
#define BN 4096
#define UN 256
#define DN 128
#define NROW 8          // x-rows per block
#define BLOCK 256       // one thread per u

__global__ __launch_bounds__(BLOCK) void hyp_logistic_kernel(
    const float* __restrict__ x,     // [B, D]
    const float* __restrict__ W,     // [U, D]
    const float* __restrict__ bias,  // [U, D]
    float* __restrict__ out)         // [B, U]
{
    __shared__ __align__(16) float x_lds[NROW][DN];
    __shared__ float logits[NROW][UN];
    __shared__ float nv2_lds[NROW];

    const int t  = threadIdx.x;        // u index
    const int b0 = blockIdx.x * NROW;  // first row of this block

    // ---- stage x rows: NROW*DN = 1024 floats, 256 threads x float4, coalesced
    {
        const float4* xg = (const float4*)(x + (size_t)b0 * DN);
        ((float4*)&x_lds[0][0])[t] = xg[t];
    }
    __syncthreads();

    // ---- nv2 per row (first NROW threads; broadcast via LDS)
    if (t < NROW) {
        float s = 0.f;
        #pragma unroll
        for (int d = 0; d < DN; ++d) { float v = x_lds[t][d]; s += v * v; }
        nv2_lds[t] = s;
    }
    // (no barrier yet; barrier after the main loop covers visibility)

    // ---- main accumulation: dots over D plus fused per-u scalars
    float dot1[NROW];  // x . W[u]
    float dot2[NROW];  // x . bias[u]
    #pragma unroll
    for (int r = 0; r < NROW; ++r) { dot1[r] = 0.f; dot2[r] = 0.f; }
    float nb2 = 0.f, bw = 0.f, wn2 = 0.f;

    const float4* Wg = (const float4*)(W    + (size_t)t * DN);  // 32 float4
    const float4* Bg = (const float4*)(bias + (size_t)t * DN);

    #pragma unroll
    for (int c = 0; c < DN / 16; ++c) {   // 8 chunks of 16 floats
        float4 w4[4], b4[4];
        #pragma unroll
        for (int j = 0; j < 4; ++j) { w4[j] = Wg[c * 4 + j]; b4[j] = Bg[c * 4 + j]; }

        #pragma unroll
        for (int j = 0; j < 4; ++j) {
            nb2 += b4[j].x*b4[j].x + b4[j].y*b4[j].y + b4[j].z*b4[j].z + b4[j].w*b4[j].w;
            bw  += b4[j].x*w4[j].x + b4[j].y*w4[j].y + b4[j].z*w4[j].z + b4[j].w*w4[j].w;
            wn2 += w4[j].x*w4[j].x + w4[j].y*w4[j].y + w4[j].z*w4[j].z + w4[j].w*w4[j].w;
        }

        #pragma unroll
        for (int r = 0; r < NROW; ++r) {
            const float4* xr = (const float4*)&x_lds[r][c * 16];
            #pragma unroll
            for (int j = 0; j < 4; ++j) {
                float4 xv = xr[j];   // wave-uniform broadcast read
                dot1[r] += xv.x*w4[j].x + xv.y*w4[j].y + xv.z*w4[j].z + xv.w*w4[j].w;
                dot2[r] += xv.x*b4[j].x + xv.y*b4[j].y + xv.z*b4[j].z + xv.w*b4[j].w;
            }
        }
    }
    __syncthreads();  // nv2_lds now visible to all

    // ---- per-(b,u) epilogue
    const float one_m_nb2 = 1.0f - nb2;
    const float wnorm  = sqrtf(wn2);
    const float a_norm = fabsf(one_m_nb2) * wnorm;        // ||a_k||
    const float lam    = 2.0f / one_m_nb2;
    const float scale  = lam * a_norm;                    // = 2*wnorm when nb2<1

    #pragma unroll
    for (int r = 0; r < NROW; ++r) {
        const float nv2 = nv2_lds[r];
        const float xy  = -dot2[r];
        const float dd  = 1.0f + 2.0f * xy + nb2 * nv2;
        const float inv_dd = 1.0f / dd;
        const float alpha  = (1.0f + 2.0f * xy + nv2) * inv_dd;
        const float beta   = one_m_nb2 * inv_dd;
        const float num = 2.0f * one_m_nb2 * (beta * dot1[r] - alpha * bw);
        const float mm  = alpha * alpha * nb2 + 2.0f * alpha * beta * xy
                        + beta * beta * nv2;
        const float den = (1.0f - mm) * a_norm;
        logits[r][t] = scale * asinhf(num / den);
    }
    __syncthreads();

    // ---- softmax over U=256 per row; wave w handles rows w, w+4
    const int wave = t >> 6;
    const int lane = t & 63;
    for (int r = wave; r < NROW; r += 4) {
        float v0 = logits[r][lane];
        float v1 = logits[r][lane + 64];
        float v2 = logits[r][lane + 128];
        float v3 = logits[r][lane + 192];
        float mx = fmaxf(fmaxf(v0, v1), fmaxf(v2, v3));
        #pragma unroll
        for (int off = 32; off; off >>= 1) mx = fmaxf(mx, __shfl_xor(mx, off));
        float e0 = expf(v0 - mx), e1 = expf(v1 - mx);
        float e2 = expf(v2 - mx), e3 = expf(v3 - mx);
        float s = e0 + e1 + e2 + e3;
        #pragma unroll
        for (int off = 32; off; off >>= 1) s += __shfl_xor(s, off);
        const float inv = 1.0f / s;
        float* o = out + (size_t)(b0 + r) * UN;
        o[lane]       = e0 * inv;
        o[lane + 64]  = e1 * inv;
        o[lane + 128] = e2 * inv;
        o[lane + 192] = e3 * inv;
    }
}

extern "C" void kernel_launch(void* const* d_in, const int* in_sizes, int n_in,
                              void* d_out, int out_size, void* d_ws, size_t ws_size,
                              hipStream_t stream) {
    const float* x    = (const float*)d_in[0];
    const float* W    = (const float*)d_in[1];
    const float* bias = (const float*)d_in[2];
    float* out = (float*)d_out;
    dim3 grid(BN / NROW);   // 512 blocks
    dim3 block(BLOCK);
    hipLaunchKernelGGL(hyp_logistic_kernel, grid, block, 0, stream, x, W, bias, out);
}

// Round 2
// 79.343 us; speedup vs baseline: 1.0831x; 1.0831x over previous
//
#include <hip/hip_runtime.h>
#include <hip/hip_bf16.h>
#include <math.h>

// Problem constants (B,U,D) = (4096, 256, 128)
#define BN 4096
#define UN 256
#define DN 128
#define NROW 16         // x-rows per block (halves W/bias L2 refetch vs 8)
#define BLOCK 256       // one thread per u

__global__ __launch_bounds__(BLOCK) void hyp_logistic_kernel(
    const float* __restrict__ x,     // [B, D]
    const float* __restrict__ W,     // [U, D]
    const float* __restrict__ bias,  // [U, D]
    float* __restrict__ out)         // [B, U]
{
    __shared__ __align__(16) float x_lds[NROW][DN];   // 8 KB
    __shared__ float logits[NROW][UN];                // 16 KB
    __shared__ float nv2_lds[NROW];

    const int t  = threadIdx.x;        // u index
    const int b0 = blockIdx.x * NROW;  // first row of this block

    // ---- stage x rows: NROW*DN = 2048 floats = 512 float4, 2 per thread
    {
        const float4* xg = (const float4*)(x + (size_t)b0 * DN);
        float4* xl = (float4*)&x_lds[0][0];
        xl[t]         = xg[t];
        xl[t + BLOCK] = xg[t + BLOCK];
    }
    __syncthreads();

    // ---- nv2 per row (first NROW threads; broadcast later via LDS)
    if (t < NROW) {
        float s = 0.f;
        #pragma unroll
        for (int d = 0; d < DN; ++d) { float v = x_lds[t][d]; s += v * v; }
        nv2_lds[t] = s;
    }

    // ---- main accumulation: dots over D plus fused per-u scalars
    float dot1[NROW];  // x . W[u]
    float dot2[NROW];  // x . bias[u]
    #pragma unroll
    for (int r = 0; r < NROW; ++r) { dot1[r] = 0.f; dot2[r] = 0.f; }
    float nb2 = 0.f, bw = 0.f, wn2 = 0.f;

    const float4* Wg = (const float4*)(W    + (size_t)t * DN);  // 32 float4
    const float4* Bg = (const float4*)(bias + (size_t)t * DN);

    #pragma unroll
    for (int c = 0; c < 32; c += 2) {   // 16 chunks of 8 floats
        float4 w0 = Wg[c], w1 = Wg[c + 1];
        float4 bv0 = Bg[c], bv1 = Bg[c + 1];

        nb2 += bv0.x*bv0.x + bv0.y*bv0.y + bv0.z*bv0.z + bv0.w*bv0.w
             + bv1.x*bv1.x + bv1.y*bv1.y + bv1.z*bv1.z + bv1.w*bv1.w;
        bw  += bv0.x*w0.x + bv0.y*w0.y + bv0.z*w0.z + bv0.w*w0.w
             + bv1.x*w1.x + bv1.y*w1.y + bv1.z*w1.z + bv1.w*w1.w;
        wn2 += w0.x*w0.x + w0.y*w0.y + w0.z*w0.z + w0.w*w0.w
             + w1.x*w1.x + w1.y*w1.y + w1.z*w1.z + w1.w*w1.w;

        #pragma unroll
        for (int r = 0; r < NROW; ++r) {
            const float4* xr = (const float4*)&x_lds[r][c * 4];
            float4 x0 = xr[0], x1 = xr[1];   // wave-uniform broadcast reads
            dot1[r] += x0.x*w0.x + x0.y*w0.y + x0.z*w0.z + x0.w*w0.w
                     + x1.x*w1.x + x1.y*w1.y + x1.z*w1.z + x1.w*w1.w;
            dot2[r] += x0.x*bv0.x + x0.y*bv0.y + x0.z*bv0.z + x0.w*bv0.w
                     + x1.x*bv1.x + x1.y*bv1.y + x1.z*bv1.z + x1.w*bv1.w;
        }
    }
    __syncthreads();  // nv2_lds now visible to all

    // ---- per-(b,u) epilogue (fast native transcendentals; ~2 ulp each,
    //      error budget: absmax 6.1e-5 vs threshold 2.26e-4)
    const float one_m_nb2 = 1.0f - nb2;
    const float wnorm  = sqrtf(wn2);
    const float a_norm = fabsf(one_m_nb2) * wnorm;        // ||a_k||
    const float scale  = (2.0f / one_m_nb2) * a_norm;

    #pragma unroll
    for (int r = 0; r < NROW; ++r) {
        const float nv2 = nv2_lds[r];
        const float xy  = -dot2[r];
        const float dd  = 1.0f + 2.0f * xy + nb2 * nv2;
        const float inv_dd = __builtin_amdgcn_rcpf(dd);
        const float alpha  = (1.0f + 2.0f * xy + nv2) * inv_dd;
        const float beta   = one_m_nb2 * inv_dd;
        const float num = 2.0f * one_m_nb2 * (beta * dot1[r] - alpha * bw);
        const float mm  = alpha * alpha * nb2 + 2.0f * alpha * beta * xy
                        + beta * beta * nv2;
        const float den = (1.0f - mm) * a_norm;
        // asinh(z) = sign(z) * ln(|z| + sqrt(z^2+1))
        const float z  = num * __builtin_amdgcn_rcpf(den);
        const float az = fabsf(z);
        const float s  = sqrtf(fmaf(z, z, 1.0f));
        logits[r][t] = scale * copysignf(__logf(az + s), z);
    }
    __syncthreads();

    // ---- softmax over U=256 per row; wave w handles rows w, w+4, w+8, w+12
    const int wave = t >> 6;
    const int lane = t & 63;
    for (int r = wave; r < NROW; r += 4) {
        float v0 = logits[r][lane];
        float v1 = logits[r][lane + 64];
        float v2 = logits[r][lane + 128];
        float v3 = logits[r][lane + 192];
        float mx = fmaxf(fmaxf(v0, v1), fmaxf(v2, v3));
        #pragma unroll
        for (int off = 32; off; off >>= 1) mx = fmaxf(mx, __shfl_xor(mx, off));
        float e0 = __expf(v0 - mx), e1 = __expf(v1 - mx);
        float e2 = __expf(v2 - mx), e3 = __expf(v3 - mx);
        float s = e0 + e1 + e2 + e3;
        #pragma unroll
        for (int off = 32; off; off >>= 1) s += __shfl_xor(s, off);
        const float inv = __builtin_amdgcn_rcpf(s);
        float* o = out + (size_t)(b0 + r) * UN;
        o[lane]       = e0 * inv;
        o[lane + 64]  = e1 * inv;
        o[lane + 128] = e2 * inv;
        o[lane + 192] = e3 * inv;
    }
}

extern "C" void kernel_launch(void* const* d_in, const int* in_sizes, int n_in,
                              void* d_out, int out_size, void* d_ws, size_t ws_size,
                              hipStream_t stream) {
    const float* x    = (const float*)d_in[0];
    const float* W    = (const float*)d_in[1];
    const float* bias = (const float*)d_in[2];
    float* out = (float*)d_out;
    dim3 grid(BN / NROW);   // 256 blocks
    dim3 block(BLOCK);
    hipLaunchKernelGGL(hyp_logistic_kernel, grid, block, 0, stream, x, W, bias, out);
}

// Round 3
// 68.759 us; speedup vs baseline: 1.2498x; 1.1539x over previous
//
#include <hip/hip_runtime.h>
#include <hip/hip_bf16.h>
#include <math.h>

// Problem constants (B,U,D) = (4096, 256, 128)
#define BN 4096
#define UN 256
#define DN 128
#define MROW 16       // batch rows per block (one M=16 MFMA tile)
#define BLOCK 256

typedef __attribute__((ext_vector_type(8))) short short8x;   // 8 bf16 (4 VGPRs)
typedef __attribute__((ext_vector_type(4))) float float4x;   // MFMA C/D

// d_ws layout:
//   [0)       Wb  bf16[256][128]  65536 B
//   [65536)   Bb  bf16[256][128]  65536 B
//   [131072)  S   float4[256]     (nb2, bw, wn2, 0)  exact f32 per-u scalars

__device__ inline ushort f2bf(float f) {
    __hip_bfloat16 h = __float2bfloat16(f);
    return *(ushort*)&h;
}
__device__ inline uint pack2bf(float a, float b) {
    return (uint)f2bf(a) | ((uint)f2bf(b) << 16);
}

// ---------------- prep: W/bias -> bf16, per-u exact scalars ----------------
__global__ __launch_bounds__(64) void prep_kernel(
    const float* __restrict__ W, const float* __restrict__ bias,
    ushort* __restrict__ Wb, ushort* __restrict__ Bb, float4* __restrict__ S)
{
    const int u = blockIdx.x;
    const int l = threadIdx.x;
    const float2 w2 = ((const float2*)(W    + (size_t)u * DN))[l];
    const float2 b2 = ((const float2*)(bias + (size_t)u * DN))[l];
    float nb2 = b2.x*b2.x + b2.y*b2.y;
    float bw  = b2.x*w2.x + b2.y*w2.y;
    float wn2 = w2.x*w2.x + w2.y*w2.y;
    #pragma unroll
    for (int off = 32; off; off >>= 1) {
        nb2 += __shfl_xor(nb2, off);
        bw  += __shfl_xor(bw , off);
        wn2 += __shfl_xor(wn2, off);
    }
    ((uint*)(Wb + (size_t)u * DN))[l] = pack2bf(w2.x, w2.y);
    ((uint*)(Bb + (size_t)u * DN))[l] = pack2bf(b2.x, b2.y);
    if (l == 0) S[u] = make_float4(nb2, bw, wn2, 0.f);
}

// ---------------- main: MFMA dots + epilogue + softmax ----------------
__global__ __launch_bounds__(BLOCK) void main_kernel(
    const float* __restrict__ x,
    const ushort* __restrict__ Wb, const ushort* __restrict__ Bb,
    const float4* __restrict__ S, float* __restrict__ out)
{
    __shared__ __align__(16) ushort xa[MROW][DN + 8];  // A-operand bf16, +8 pad
    __shared__ float4 s_lds[UN];                       // per-u (nb2,bw,wn2)
    __shared__ float  nv2_lds[MROW];
    __shared__ float  logits[MROW][UN];

    const int t    = threadIdx.x;
    const int lane = t & 63;
    const int wave = t >> 6;
    const int b0   = blockIdx.x * MROW;

    // stage per-u scalar table (1 float4/thread)
    s_lds[t] = S[t];

    // stage x: thread t handles row r = t>>4, 8 floats at col (t&15)*8
    {
        const int r = t >> 4, c = (t & 15) * 8;
        const float4* xp = (const float4*)(x + (size_t)(b0 + r) * DN + c);
        const float4 a = xp[0], b = xp[1];
        float sq = a.x*a.x + a.y*a.y + a.z*a.z + a.w*a.w
                 + b.x*b.x + b.y*b.y + b.z*b.z + b.w*b.w;
        uint4 p;
        p.x = pack2bf(a.x, a.y);  p.y = pack2bf(a.z, a.w);
        p.z = pack2bf(b.x, b.y);  p.w = pack2bf(b.z, b.w);
        *(uint4*)&xa[r][c] = p;
        // reduce x^2 over the 16 threads sharing row r (lane bits 0-3)
        #pragma unroll
        for (int off = 1; off < 16; off <<= 1) sq += __shfl_xor(sq, off);
        if ((t & 15) == 0) nv2_lds[r] = sq;  // exact f32 nv2
    }
    __syncthreads();

    // ---- MFMA: D[m][u] for m = batch row (16), u = this wave's 4 tiles of 16
    const int m16 = lane & 15;   // A row / B col within tile
    const int q   = lane >> 4;   // quad
    float4x accW[4], accB[4];
    #pragma unroll
    for (int i = 0; i < 4; ++i)
        #pragma unroll
        for (int j = 0; j < 4; ++j) { accW[i][j] = 0.f; accB[i][j] = 0.f; }

    const ushort* xrow = &xa[m16][q * 8];
    #pragma unroll
    for (int ks = 0; ks < 4; ++ks) {
        const short8x afrag = *(const short8x*)(xrow + ks * 32);
        #pragma unroll
        for (int i = 0; i < 4; ++i) {
            const int u   = (wave * 4 + i) * 16 + m16;
            const int off = u * DN + ks * 32 + q * 8;
            const short8x wfrag = *(const short8x*)(Wb + off);
            const short8x bfrag = *(const short8x*)(Bb + off);
            accW[i] = __builtin_amdgcn_mfma_f32_16x16x32_bf16(afrag, wfrag, accW[i], 0, 0, 0);
            accB[i] = __builtin_amdgcn_mfma_f32_16x16x32_bf16(afrag, bfrag, accB[i], 0, 0, 0);
        }
    }

    // ---- epilogue: lane holds (u = tile*16 + m16, rows q*4+reg)
    #pragma unroll
    for (int i = 0; i < 4; ++i) {
        const int u = (wave * 4 + i) * 16 + m16;
        const float4 sc = s_lds[u];
        const float nb2 = sc.x, bw = sc.y, wn2 = sc.z;
        const float one_m  = 1.0f - nb2;
        const float a_norm = fabsf(one_m) * sqrtf(wn2);
        const float scale  = (2.0f / one_m) * a_norm;
        #pragma unroll
        for (int rg = 0; rg < 4; ++rg) {
            const int   mr   = q * 4 + rg;
            const float nv2  = nv2_lds[mr];
            const float dot1 = accW[i][rg];
            const float xy   = -accB[i][rg];
            const float dd   = 1.0f + 2.0f * xy + nb2 * nv2;
            const float inv_dd = __builtin_amdgcn_rcpf(dd);
            const float alpha  = (1.0f + 2.0f * xy + nv2) * inv_dd;
            const float beta   = one_m * inv_dd;
            const float num = 2.0f * one_m * (beta * dot1 - alpha * bw);
            const float mm  = alpha * alpha * nb2 + 2.0f * alpha * beta * xy
                            + beta * beta * nv2;
            const float den = (1.0f - mm) * a_norm;
            const float z   = num * __builtin_amdgcn_rcpf(den);
            const float s   = sqrtf(fmaf(z, z, 1.0f));
            logits[mr][u] = scale * copysignf(__logf(fabsf(z) + s), z);
        }
    }
    __syncthreads();

    // ---- softmax over U=256 per row; wave w handles rows w, w+4, w+8, w+12
    for (int r = wave; r < MROW; r += 4) {
        float v0 = logits[r][lane];
        float v1 = logits[r][lane + 64];
        float v2 = logits[r][lane + 128];
        float v3 = logits[r][lane + 192];
        float mx = fmaxf(fmaxf(v0, v1), fmaxf(v2, v3));
        #pragma unroll
        for (int off = 32; off; off >>= 1) mx = fmaxf(mx, __shfl_xor(mx, off));
        float e0 = __expf(v0 - mx), e1 = __expf(v1 - mx);
        float e2 = __expf(v2 - mx), e3 = __expf(v3 - mx);
        float s = e0 + e1 + e2 + e3;
        #pragma unroll
        for (int off = 32; off; off >>= 1) s += __shfl_xor(s, off);
        const float inv = __builtin_amdgcn_rcpf(s);
        float* o = out + (size_t)(b0 + r) * UN;
        o[lane]       = e0 * inv;
        o[lane + 64]  = e1 * inv;
        o[lane + 128] = e2 * inv;
        o[lane + 192] = e3 * inv;
    }
}

extern "C" void kernel_launch(void* const* d_in, const int* in_sizes, int n_in,
                              void* d_out, int out_size, void* d_ws, size_t ws_size,
                              hipStream_t stream) {
    const float* x    = (const float*)d_in[0];
    const float* W    = (const float*)d_in[1];
    const float* bias = (const float*)d_in[2];
    float* out = (float*)d_out;

    ushort* Wb = (ushort*)d_ws;
    ushort* Bb = Wb + (size_t)UN * DN;
    float4* S  = (float4*)((char*)d_ws + 2 * (size_t)UN * DN * sizeof(ushort));

    hipLaunchKernelGGL(prep_kernel, dim3(UN), dim3(64), 0, stream, W, bias, Wb, Bb, S);
    hipLaunchKernelGGL(main_kernel, dim3(BN / MROW), dim3(BLOCK), 0, stream,
                       x, Wb, Bb, S, out);
}